// Round 12
// baseline (6948.832 us; speedup 1.0000x reference)
//
#include <hip/hip_runtime.h>
#include <hip/hip_fp16.h>

#define LSEQ 4096
#define HD 256
#define GD 1024
#define NTAG 20
#define TAG_START 1
#define TAG_STOP 0
#define NEGV -10000.0f

typedef unsigned int u32;

#define USE_SDOT4 1
#if defined(__has_builtin)
#if !__has_builtin(__builtin_amdgcn_sdot4)
#undef USE_SDOT4
#define USE_SDOT4 0
#endif
#endif

__device__ __forceinline__ int sdot4(u32 a, u32 b, int c) {
#if USE_SDOT4
  return __builtin_amdgcn_sdot4((int)a, (int)b, c, false);
#else
  int r = c;
  r += ((int)(a << 24) >> 24) * ((int)(b << 24) >> 24);
  r += ((int)(a << 16) >> 24) * ((int)(b << 16) >> 24);
  r += ((int)(a << 8) >> 24) * ((int)(b << 8) >> 24);
  r += ((int)a >> 24) * ((int)b >> 24);
  return r;
#endif
}

// quantize 4 consecutive f32 weights to i8 at scale 2048, pack little-endian
__device__ __forceinline__ u32 q4(const float* w) {
  const int b0 = (int)rintf(fminf(fmaxf(w[0] * 2048.f, -127.f), 127.f));
  const int b1 = (int)rintf(fminf(fmaxf(w[1] * 2048.f, -127.f), 127.f));
  const int b2 = (int)rintf(fminf(fmaxf(w[2] * 2048.f, -127.f), 127.f));
  const int b3 = (int)rintf(fminf(fmaxf(w[3] * 2048.f, -127.f), 127.f));
  return (u32)(b0 & 255) | ((u32)(b1 & 255) << 8) | ((u32)(b2 & 255) << 16) |
         ((u32)(b3 & 255) << 24);
}

// quad_perm DPP fetches (VALU-only)
__device__ __forceinline__ float dpp_xor1(float x) {
  int y = __builtin_amdgcn_mov_dpp(__builtin_bit_cast(int, x), 0xB1, 0xF, 0xF,
                                   true);  // quad_perm(1,0,3,2)
  return __builtin_bit_cast(float, y);
}
__device__ __forceinline__ float dpp_xor2(float x) {
  int y = __builtin_amdgcn_mov_dpp(__builtin_bit_cast(int, x), 0x4E, 0xF, 0xF,
                                   true);  // quad_perm(2,3,0,1)
  return __builtin_bit_cast(float, y);
}

__device__ __forceinline__ float fsigm(float x) {
  return 1.0f / (1.0f + __expf(-x));
}
__device__ __forceinline__ float ftanh(float x) {
  float t = __expf(-2.0f * fabsf(x));
  float r = (1.0f - t) / (1.0f + t);
  return x < 0.0f ? -r : r;
}

// ---------------- K0: embedding gather ----------------
__global__ void gather_emb(const int* __restrict__ sent,
                           const float* __restrict__ etab,
                           float* __restrict__ emb) {
  const int t = blockIdx.x;
  const int l = threadIdx.x;
  const long long row = sent[t];
  *(float4*)&emb[t * HD + l * 4] = *(const float4*)&etab[row * HD + l * 4];
}

// ---------------- K1: xp = emb @ W_ih^T + (b_ih + b_hh), both dirs ----------------
__global__ __launch_bounds__(256) void xp_gemm(
    const float* __restrict__ emb, const float* __restrict__ Wf,
    const float* __restrict__ Wb, const float* __restrict__ bihf,
    const float* __restrict__ bhhf, const float* __restrict__ bihb,
    const float* __restrict__ bhhb, float* __restrict__ xpf,
    float* __restrict__ xpb) {
  const int dir = blockIdx.z;
  const float* __restrict__ W = dir ? Wb : Wf;
  const float* __restrict__ b1 = dir ? bihb : bihf;
  const float* __restrict__ b2 = dir ? bhhb : bhhf;
  float* __restrict__ out = dir ? xpb : xpf;
  __shared__ float As[32][64];
  __shared__ float Bs[32][64];
  const int bm = blockIdx.y * 64;
  const int bn = blockIdx.x * 64;
  const int tid = threadIdx.x;
  const int tx = tid & 15, ty = tid >> 4;
  const int lm = tid & 63, lk = tid >> 6;  // loader: row lm, k-quad lk
  float acc[4][4];
#pragma unroll
  for (int i = 0; i < 4; ++i)
#pragma unroll
    for (int j = 0; j < 4; ++j) acc[i][j] = 0.0f;

  for (int k0 = 0; k0 < HD; k0 += 32) {
    float4 a0 = *(const float4*)&emb[(bm + lm) * HD + k0 + lk * 4];
    float4 a1 = *(const float4*)&emb[(bm + lm) * HD + k0 + 16 + lk * 4];
    float4 c0 = *(const float4*)&W[(bn + lm) * HD + k0 + lk * 4];
    float4 c1 = *(const float4*)&W[(bn + lm) * HD + k0 + 16 + lk * 4];
    __syncthreads();
    As[lk * 4 + 0][lm] = a0.x;
    As[lk * 4 + 1][lm] = a0.y;
    As[lk * 4 + 2][lm] = a0.z;
    As[lk * 4 + 3][lm] = a0.w;
    As[16 + lk * 4 + 0][lm] = a1.x;
    As[16 + lk * 4 + 1][lm] = a1.y;
    As[16 + lk * 4 + 2][lm] = a1.z;
    As[16 + lk * 4 + 3][lm] = a1.w;
    Bs[lk * 4 + 0][lm] = c0.x;
    Bs[lk * 4 + 1][lm] = c0.y;
    Bs[lk * 4 + 2][lm] = c0.z;
    Bs[lk * 4 + 3][lm] = c0.w;
    Bs[16 + lk * 4 + 0][lm] = c1.x;
    Bs[16 + lk * 4 + 1][lm] = c1.y;
    Bs[16 + lk * 4 + 2][lm] = c1.z;
    Bs[16 + lk * 4 + 3][lm] = c1.w;
    __syncthreads();
#pragma unroll
    for (int k = 0; k < 32; ++k) {
      float4 av = *(const float4*)&As[k][ty * 4];
      float4 bv = *(const float4*)&Bs[k][tx * 4];
      float am[4] = {av.x, av.y, av.z, av.w};
      float bn_[4] = {bv.x, bv.y, bv.z, bv.w};
#pragma unroll
      for (int i = 0; i < 4; ++i)
#pragma unroll
        for (int j = 0; j < 4; ++j) acc[i][j] += am[i] * bn_[j];
    }
  }
#pragma unroll
  for (int i = 0; i < 4; ++i) {
    const int m = bm + ty * 4 + i;
#pragma unroll
    for (int j = 0; j < 4; ++j) {
      const int n = bn + tx * 4 + j;
      out[m * GD + n] = acc[i][j] + b1[n] + b2[n];
    }
  }
}

// ---------------- K2: BiLSTM scan, int8 resident + quad-gate fusion ----------
// One WG (1024 thr, 16 waves) per direction. Thread t -> quad lane q=t&3,
// element e=t>>2; owns z-row q*256+e (gate q of element e), full 256-wide i8
// weight row resident in 16 named uint4 (64 regs, fits the 128-unified cap).
// Each thread adds its own xp term, then 3 quad DPP movs give lane q=0 all 4
// pre-activations -> gates in-register on all 16 waves. No zbuf, ONE barrier.
__global__ __launch_bounds__(1024) void lstm_scan(
    const float* __restrict__ Whhf, const float* __restrict__ Whhb,
    const float* __restrict__ xpf, const float* __restrict__ xpb,
    const float* __restrict__ h0, const float* __restrict__ c0,
    float* __restrict__ hf, float* __restrict__ hb) {
  const int dir = blockIdx.x;
  const float* __restrict__ Whh = dir ? Whhb : Whhf;
  const float* __restrict__ xp = dir ? xpb : xpf;
  float* __restrict__ hout = dir ? hb : hf;
  const int t = threadIdx.x;
  const int q = t & 3;   // gate index (0:i 1:f 2:g 3:o)
  const int e = t >> 2;  // element 0..255
  const int row = q * HD + e;  // owned z-row

  __shared__ __align__(16) u32 hq[2][64];  // packed i8 h, ping-pong (512 B)

  // resident weight row: 16 named uint4 (64 VGPRs)
  uint4 wA0, wA1, wA2, wA3, wA4, wA5, wA6, wA7;
  uint4 wA8, wA9, wA10, wA11, wA12, wA13, wA14, wA15;
#define LW(j)                                             \
  {                                                       \
    const float* s0 = &Whh[(size_t)row * HD + (j) * 16];  \
    wA##j.x = q4(s0);                                     \
    wA##j.y = q4(s0 + 4);                                 \
    wA##j.z = q4(s0 + 8);                                 \
    wA##j.w = q4(s0 + 12);                                \
  }
  LW(0) LW(1) LW(2) LW(3) LW(4) LW(5) LW(6) LW(7)
  LW(8) LW(9) LW(10) LW(11) LW(12) LW(13) LW(14) LW(15)
#undef LW

  float cst = 0.0f;
  if (q == 0) cst = c0[dir * HD + e];
  if (t < HD) {
    const int hq0 =
        (int)rintf(fminf(fmaxf(h0[dir * HD + t] * 16.f, -127.f), 127.f));
    ((unsigned char*)&hq[0][0])[t] = (unsigned char)(hq0 & 255);
  }
  __syncthreads();

  for (int s = 0; s < LSEQ; ++s) {
    const int tt = dir ? (LSEQ - 1 - s) : s;
    const int par = s & 1;
    const float dq =
        (s == 0) ? (1.f / (2048.f * 16.f)) : (1.f / (2048.f * 127.f));
    // per-thread xp term for the owned row (issued early, used post-matvec)
    const float xg = xp[(size_t)tt * GD + row];
    const uint4* hq4 = (const uint4*)&hq[par][0];
    int acA = 0, acB = 0, acC = 0, acD = 0;  // 4 chains to break dep latency
#define MV(j, AC)                      \
  {                                    \
    const uint4 hv = hq4[j];           \
    AC = sdot4(wA##j.x, hv.x, AC);     \
    AC = sdot4(wA##j.y, hv.y, AC);     \
    AC = sdot4(wA##j.z, hv.z, AC);     \
    AC = sdot4(wA##j.w, hv.w, AC);     \
  }
    MV(0, acA) MV(1, acB) MV(2, acC) MV(3, acD)
    MV(4, acA) MV(5, acB) MV(6, acC) MV(7, acD)
    MV(8, acA) MV(9, acB) MV(10, acC) MV(11, acD)
    MV(12, acA) MV(13, acB) MV(14, acC) MV(15, acD)
#undef MV
    const int acc = (acA + acB) + (acC + acD);
    const float z = (float)acc * dq + xg;  // pre-activation of row (gate q, elem e)
    // quad exchange: lane q=0 collects {i,f,g,o}
    const float zx1 = dpp_xor1(z);              // from lane^1
    const float zx2 = dpp_xor2(z);              // from lane^2
    const float zx3 = dpp_xor1(zx2);            // from lane^3
    if (q == 0) {
      const float ig = fsigm(z), fg = fsigm(zx1), gg = ftanh(zx2),
                  og = fsigm(zx3);
      const float cv = fg * cst + ig * gg;
      cst = cv;
      const float hv = og * ftanh(cv);
      hout[(size_t)tt * HD + e] = hv;
      const int hqv = (int)rintf(fminf(fmaxf(hv * 127.f, -127.f), 127.f));
      ((unsigned char*)&hq[par ^ 1][0])[e] = (unsigned char)(hqv & 255);
    }
    __syncthreads();  // single barrier: next-step h ready (ping-pong safe)
  }
}

// ---------------- K3: feats = [hf|hb] @ W_out^T + b_out ----------------
__global__ __launch_bounds__(256) void feats_kernel(
    const float* __restrict__ hf, const float* __restrict__ hb,
    const float* __restrict__ Wout, const float* __restrict__ bout,
    float* __restrict__ feats) {
  __shared__ float Ws[NTAG][520];  // padded: avoid 20-way bank conflict
  __shared__ float bs[NTAG];
  const int tid = threadIdx.x;
  for (int i = tid; i < NTAG * 512; i += 256) Ws[i / 512][i % 512] = Wout[i];
  if (tid < NTAG) bs[tid] = bout[tid];
  __syncthreads();
  const int t0 = blockIdx.x * 32;
  for (int idx = tid; idx < 32 * NTAG; idx += 256) {
    const int t = t0 + idx / NTAG;
    const int tag = idx % NTAG;
    const float* __restrict__ hfr = &hf[t * HD];
    const float* __restrict__ hbr = &hb[t * HD];
    float s = bs[tag];
#pragma unroll 8
    for (int k = 0; k < HD; ++k) {
      s += hfr[k] * Ws[tag][k];
      s += hbr[k] * Ws[tag][HD + k];
    }
    feats[t * NTAG + tag] = s;
  }
}

// ---------------- K4: Viterbi decode (single wave) + chunked backtrack --------
__global__ __launch_bounds__(64) void viterbi_kernel(
    const float* __restrict__ feats, const float* __restrict__ trans,
    float* __restrict__ out) {
  __shared__ unsigned char bp[LSEQ * NTAG];  // 80 KB backpointers
  __shared__ float fvb[32];
  __shared__ float termb[32];
  __shared__ unsigned char fmap[64][NTAG];
  __shared__ unsigned char bnd[64];
  const int lane = threadIdx.x;
  const int nt = lane < NTAG ? lane : 0;
  float tr[NTAG];
#pragma unroll
  for (int p = 0; p < NTAG; ++p) tr[p] = trans[nt * NTAG + p];
  if (lane < NTAG) fvb[lane] = (lane == TAG_START) ? 0.0f : NEGV;
  __syncthreads();

  float fcur[8], fnxt[8];
#pragma unroll
  for (int i = 0; i < 8; ++i) fcur[i] = feats[i * NTAG + nt];
  for (int t0 = 0; t0 < LSEQ; t0 += 8) {
#pragma unroll
    for (int i = 0; i < 8; ++i) {
      const int tt = t0 + 8 + i;
      fnxt[i] = (tt < LSEQ) ? feats[tt * NTAG + nt] : 0.0f;
    }
#pragma unroll
    for (int i = 0; i < 8; ++i) {
      const int t = t0 + i;
      float best = fvb[0] + tr[0];
      int bi = 0;
#pragma unroll
      for (int p = 1; p < NTAG; ++p) {
        const float v = fvb[p] + tr[p];
        if (v > best) {
          best = v;
          bi = p;
        }
      }
      const float nv = best + fcur[i];
      if (lane < NTAG) {
        fvb[lane] = nv;
        bp[t * NTAG + lane] = (unsigned char)bi;
      }
    }
#pragma unroll
    for (int i = 0; i < 8; ++i) fcur[i] = fnxt[i];
  }

  if (lane < NTAG) termb[lane] = fvb[lane] + trans[TAG_STOP * NTAG + lane];
  __syncthreads();
  if (lane == 0) {
    float best = termb[0];
    int bi = 0;
#pragma unroll
    for (int p = 1; p < NTAG; ++p) {
      const float v = termb[p];
      if (v > best) {
        best = v;
        bi = p;
      }
    }
    out[0] = best;
    bnd[63] = (unsigned char)bi;
  }
  __syncthreads();

  // compose per-chunk backpointer maps (64 steps each) in parallel
  {
    const int c = lane;
    int m[NTAG];
#pragma unroll
    for (int e = 0; e < NTAG; ++e) m[e] = e;
    for (int s = 63; s >= 0; --s) {
      const int base = (c * 64 + s) * NTAG;
#pragma unroll
      for (int e = 0; e < NTAG; ++e) m[e] = bp[base + m[e]];
    }
#pragma unroll
    for (int e = 0; e < NTAG; ++e) fmap[c][e] = (unsigned char)m[e];
  }
  __syncthreads();
  if (lane == 0) {
    for (int cc = 63; cc >= 1; --cc) bnd[cc - 1] = fmap[cc][bnd[cc]];
  }
  __syncthreads();
  // per-lane backtrack inside own chunk
  {
    const int c = lane;
    int cur = bnd[c];
    out[1 + c * 64 + 63] = (float)cur;
    for (int s2 = 63; s2 >= 1; --s2) {
      cur = bp[(c * 64 + s2) * NTAG + cur];
      out[1 + c * 64 + s2 - 1] = (float)cur;
    }
  }
}

extern "C" void kernel_launch(void* const* d_in, const int* in_sizes, int n_in,
                              void* d_out, int out_size, void* d_ws,
                              size_t ws_size, hipStream_t stream) {
  const int* sentence = (const int*)d_in[0];
  const float* etab = (const float*)d_in[1];
  const float* Wihf = (const float*)d_in[2];
  const float* Whhf = (const float*)d_in[3];
  const float* bihf = (const float*)d_in[4];
  const float* bhhf = (const float*)d_in[5];
  const float* Wihb = (const float*)d_in[6];
  const float* Whhb = (const float*)d_in[7];
  const float* bihb = (const float*)d_in[8];
  const float* bhhb = (const float*)d_in[9];
  const float* Wout = (const float*)d_in[10];
  const float* bout = (const float*)d_in[11];
  const float* trans = (const float*)d_in[12];
  const float* h0 = (const float*)d_in[13];
  const float* c0 = (const float*)d_in[14];

  float* ws = (float*)d_ws;
  float* xpf = ws;
  float* xpb = xpf + (size_t)LSEQ * GD;
  float* hfp = xpb + (size_t)LSEQ * GD;
  float* hbp = hfp + (size_t)LSEQ * HD;
  float* emb = hbp + (size_t)LSEQ * HD;
  float* feats = emb + (size_t)LSEQ * HD;
  float* outp = (float*)d_out;

  gather_emb<<<LSEQ, 64, 0, stream>>>(sentence, etab, emb);
  xp_gemm<<<dim3(GD / 64, LSEQ / 64, 2), 256, 0, stream>>>(
      emb, Wihf, Wihb, bihf, bhhf, bihb, bhhb, xpf, xpb);
  lstm_scan<<<2, 1024, 0, stream>>>(Whhf, Whhb, xpf, xpb, h0, c0, hfp, hbp);
  feats_kernel<<<LSEQ / 32, 256, 0, stream>>>(hfp, hbp, Wout, bout, feats);
  viterbi_kernel<<<1, 64, 0, stream>>>(feats, trans, outp);
}

// Round 13
// 5334.299 us; speedup vs baseline: 1.3027x; 1.3027x over previous
//
#include <hip/hip_runtime.h>
#include <hip/hip_fp16.h>

#define LSEQ 4096
#define HD 256
#define GD 1024
#define NTAG 20
#define TAG_START 1
#define TAG_STOP 0
#define NEGV -10000.0f

typedef unsigned int u32;

#define USE_SDOT4 1
#if defined(__has_builtin)
#if !__has_builtin(__builtin_amdgcn_sdot4)
#undef USE_SDOT4
#define USE_SDOT4 0
#endif
#endif

__device__ __forceinline__ int sdot4(u32 a, u32 b, int c) {
#if USE_SDOT4
  return __builtin_amdgcn_sdot4((int)a, (int)b, c, false);
#else
  int r = c;
  r += ((int)(a << 24) >> 24) * ((int)(b << 24) >> 24);
  r += ((int)(a << 16) >> 24) * ((int)(b << 16) >> 24);
  r += ((int)(a << 8) >> 24) * ((int)(b << 8) >> 24);
  r += ((int)a >> 24) * ((int)b >> 24);
  return r;
#endif
}

// quantize 4 consecutive f32 weights to i8 at scale 2048, pack little-endian
__device__ __forceinline__ u32 q4(const float* w) {
  const int b0 = (int)rintf(fminf(fmaxf(w[0] * 2048.f, -127.f), 127.f));
  const int b1 = (int)rintf(fminf(fmaxf(w[1] * 2048.f, -127.f), 127.f));
  const int b2 = (int)rintf(fminf(fmaxf(w[2] * 2048.f, -127.f), 127.f));
  const int b3 = (int)rintf(fminf(fmaxf(w[3] * 2048.f, -127.f), 127.f));
  return (u32)(b0 & 255) | ((u32)(b1 & 255) << 8) | ((u32)(b2 & 255) << 16) |
         ((u32)(b3 & 255) << 24);
}

__device__ __forceinline__ float fsigm(float x) {
  return 1.0f / (1.0f + __expf(-x));
}
__device__ __forceinline__ float ftanh(float x) {
  float t = __expf(-2.0f * fabsf(x));
  float r = (1.0f - t) / (1.0f + t);
  return x < 0.0f ? -r : r;
}

// ---------------- K1: xp = emb @ W_ih^T + biases, gather fused, both dirs ----
__global__ __launch_bounds__(256) void xp_gemm(
    const int* __restrict__ sent, const float* __restrict__ etab,
    const float* __restrict__ Wf, const float* __restrict__ Wb,
    const float* __restrict__ bihf, const float* __restrict__ bhhf,
    const float* __restrict__ bihb, const float* __restrict__ bhhb,
    float* __restrict__ xpf, float* __restrict__ xpb) {
  const int dir = blockIdx.z;
  const float* __restrict__ W = dir ? Wb : Wf;
  const float* __restrict__ b1 = dir ? bihb : bihf;
  const float* __restrict__ b2 = dir ? bhhb : bhhf;
  float* __restrict__ out = dir ? xpb : xpf;
  __shared__ float As[32][64];
  __shared__ float Bs[32][64];
  const int bm = blockIdx.y * 64;
  const int bn = blockIdx.x * 64;
  const int tid = threadIdx.x;
  const int tx = tid & 15, ty = tid >> 4;
  const int lm = tid & 63, lk = tid >> 6;  // loader: row lm, k-quad lk
  const size_t arow = (size_t)sent[bm + lm] * HD;  // gather fused
  float acc[4][4];
#pragma unroll
  for (int i = 0; i < 4; ++i)
#pragma unroll
    for (int j = 0; j < 4; ++j) acc[i][j] = 0.0f;

  for (int k0 = 0; k0 < HD; k0 += 32) {
    float4 a0 = *(const float4*)&etab[arow + k0 + lk * 4];
    float4 a1 = *(const float4*)&etab[arow + k0 + 16 + lk * 4];
    float4 c0 = *(const float4*)&W[(bn + lm) * HD + k0 + lk * 4];
    float4 c1 = *(const float4*)&W[(bn + lm) * HD + k0 + 16 + lk * 4];
    __syncthreads();
    As[lk * 4 + 0][lm] = a0.x;
    As[lk * 4 + 1][lm] = a0.y;
    As[lk * 4 + 2][lm] = a0.z;
    As[lk * 4 + 3][lm] = a0.w;
    As[16 + lk * 4 + 0][lm] = a1.x;
    As[16 + lk * 4 + 1][lm] = a1.y;
    As[16 + lk * 4 + 2][lm] = a1.z;
    As[16 + lk * 4 + 3][lm] = a1.w;
    Bs[lk * 4 + 0][lm] = c0.x;
    Bs[lk * 4 + 1][lm] = c0.y;
    Bs[lk * 4 + 2][lm] = c0.z;
    Bs[lk * 4 + 3][lm] = c0.w;
    Bs[16 + lk * 4 + 0][lm] = c1.x;
    Bs[16 + lk * 4 + 1][lm] = c1.y;
    Bs[16 + lk * 4 + 2][lm] = c1.z;
    Bs[16 + lk * 4 + 3][lm] = c1.w;
    __syncthreads();
#pragma unroll
    for (int k = 0; k < 32; ++k) {
      float4 av = *(const float4*)&As[k][ty * 4];
      float4 bv = *(const float4*)&Bs[k][tx * 4];
      float am[4] = {av.x, av.y, av.z, av.w};
      float bn_[4] = {bv.x, bv.y, bv.z, bv.w};
#pragma unroll
      for (int i = 0; i < 4; ++i)
#pragma unroll
        for (int j = 0; j < 4; ++j) acc[i][j] += am[i] * bn_[j];
    }
  }
#pragma unroll
  for (int i = 0; i < 4; ++i) {
    const int m = bm + ty * 4 + i;
#pragma unroll
    for (int j = 0; j < 4; ++j) {
      const int n = bn + tx * 4 + j;
      out[m * GD + n] = acc[i][j] + b1[n] + b2[n];
    }
  }
}

// ---------------- K2: BiLSTM scan, int8, ALL weights register-resident --------
// (R10 structure, best measured: 4240 us. One WG of 1024 threads per direction,
// thread t owns z-row t with its full 256-wide i8 weight row in 16 named uint4
// = 64 regs; per-step LDS = broadcast h reads + 4 KB zbuf; gates on tid<256.)
__global__ __launch_bounds__(1024) void lstm_scan(
    const float* __restrict__ Whhf, const float* __restrict__ Whhb,
    const float* __restrict__ xpf, const float* __restrict__ xpb,
    const float* __restrict__ h0, const float* __restrict__ c0,
    float* __restrict__ hf, float* __restrict__ hb) {
  const int dir = blockIdx.x;
  const float* __restrict__ Whh = dir ? Whhb : Whhf;
  const float* __restrict__ xp = dir ? xpb : xpf;
  float* __restrict__ hout = dir ? hb : hf;
  const int t = threadIdx.x;  // z-row 0..1023

  __shared__ __align__(16) u32 hq[2][64];  // packed i8 h, ping-pong (512 B)
  __shared__ float zbuf[GD];               // 4 KB

  // resident weight row: 16 named uint4 (64 VGPRs)
  uint4 wA0, wA1, wA2, wA3, wA4, wA5, wA6, wA7;
  uint4 wA8, wA9, wA10, wA11, wA12, wA13, wA14, wA15;
#define LW(j)                                           \
  {                                                     \
    const float* s0 = &Whh[(size_t)t * HD + (j) * 16];  \
    wA##j.x = q4(s0);                                   \
    wA##j.y = q4(s0 + 4);                               \
    wA##j.z = q4(s0 + 8);                               \
    wA##j.w = q4(s0 + 12);                              \
  }
  LW(0) LW(1) LW(2) LW(3) LW(4) LW(5) LW(6) LW(7)
  LW(8) LW(9) LW(10) LW(11) LW(12) LW(13) LW(14) LW(15)
#undef LW

  float cst = 0.0f;
  if (t < HD) {
    cst = c0[dir * HD + t];
    const int hq0 =
        (int)rintf(fminf(fmaxf(h0[dir * HD + t] * 16.f, -127.f), 127.f));
    ((unsigned char*)&hq[0][0])[t] = (unsigned char)(hq0 & 255);
  }
  __syncthreads();

  for (int s = 0; s < LSEQ; ++s) {
    const int tt = dir ? (LSEQ - 1 - s) : s;
    const int par = s & 1;
    const float dq =
        (s == 0) ? (1.f / (2048.f * 16.f)) : (1.f / (2048.f * 127.f));
    // xp prefetch for the gate phase (hidden under the matvec)
    float xg0 = 0.f, xg1 = 0.f, xg2 = 0.f, xg3 = 0.f;
    if (t < HD) {
      const float* xr = &xp[(size_t)tt * GD + t];
      xg0 = xr[0];
      xg1 = xr[HD];
      xg2 = xr[2 * HD];
      xg3 = xr[3 * HD];
    }
    const uint4* hq4 = (const uint4*)&hq[par][0];
    int acc = 0;
#define MV(j)                         \
  {                                   \
    const uint4 hv = hq4[j];          \
    acc = sdot4(wA##j.x, hv.x, acc);  \
    acc = sdot4(wA##j.y, hv.y, acc);  \
    acc = sdot4(wA##j.z, hv.z, acc);  \
    acc = sdot4(wA##j.w, hv.w, acc);  \
  }
    MV(0) MV(1) MV(2) MV(3) MV(4) MV(5) MV(6) MV(7)
    MV(8) MV(9) MV(10) MV(11) MV(12) MV(13) MV(14) MV(15)
#undef MV
    zbuf[t] = (float)acc * dq;
    __syncthreads();  // A: z complete
    if (t < HD) {
      const float zi = zbuf[t] + xg0;
      const float zf = zbuf[HD + t] + xg1;
      const float zg = zbuf[2 * HD + t] + xg2;
      const float zo = zbuf[3 * HD + t] + xg3;
      const float ig = fsigm(zi), fg = fsigm(zf), gg = ftanh(zg),
                  og = fsigm(zo);
      const float cv = fg * cst + ig * gg;
      cst = cv;
      const float hv = og * ftanh(cv);
      hout[(size_t)tt * HD + t] = hv;
      const int hqv = (int)rintf(fminf(fmaxf(hv * 127.f, -127.f), 127.f));
      ((unsigned char*)&hq[par ^ 1][0])[t] = (unsigned char)(hqv & 255);
    }
    __syncthreads();  // B: next-step h ready
  }
}

// ---------------- K3: feats = [hf|hb] @ W_out^T + b_out ----------------
__global__ __launch_bounds__(256) void feats_kernel(
    const float* __restrict__ hf, const float* __restrict__ hb,
    const float* __restrict__ Wout, const float* __restrict__ bout,
    float* __restrict__ feats) {
  __shared__ float Ws[NTAG][520];  // padded: avoid 20-way bank conflict
  __shared__ float bs[NTAG];
  const int tid = threadIdx.x;
  for (int i = tid; i < NTAG * 512; i += 256) Ws[i / 512][i % 512] = Wout[i];
  if (tid < NTAG) bs[tid] = bout[tid];
  __syncthreads();
  const int t0 = blockIdx.x * 32;
  for (int idx = tid; idx < 32 * NTAG; idx += 256) {
    const int t = t0 + idx / NTAG;
    const int tag = idx % NTAG;
    const float* __restrict__ hfr = &hf[t * HD];
    const float* __restrict__ hbr = &hb[t * HD];
    float s = bs[tag];
#pragma unroll 8
    for (int k = 0; k < HD; ++k) {
      s += hfr[k] * Ws[tag][k];
      s += hbr[k] * Ws[tag][HD + k];
    }
    feats[t * NTAG + tag] = s;
  }
}

// ---------------- K4: Viterbi decode, register-resident fv (no LDS in DP) ----
// Single wave. Lane n holds fv[n]; cross-lane reads via v_readlane with
// compile-time lane index (VALU-only, no lgkmcnt RAW stall each step).
// Argmax in 4 contiguous sub-chains merged in index order with strict '>' --
// exact jnp.argmax first-max semantics. Chunked backtrack unchanged.
__global__ __launch_bounds__(64) void viterbi_kernel(
    const float* __restrict__ feats, const float* __restrict__ trans,
    float* __restrict__ out) {
  __shared__ unsigned char bp[LSEQ * NTAG];  // 80 KB backpointers
  __shared__ float termb[32];
  __shared__ unsigned char fmap[64][NTAG];
  __shared__ unsigned char bnd[64];
  const int lane = threadIdx.x;
  const int nt = lane < NTAG ? lane : 0;
  float tr[NTAG];
#pragma unroll
  for (int p = 0; p < NTAG; ++p) tr[p] = trans[nt * NTAG + p];
  float fv = (lane == TAG_START) ? 0.0f : NEGV;  // lanes >= 20 hold NEGV

  float fcur[8], fnxt[8];
#pragma unroll
  for (int i = 0; i < 8; ++i) fcur[i] = feats[i * NTAG + nt];
  for (int t0 = 0; t0 < LSEQ; t0 += 8) {
#pragma unroll
    for (int i = 0; i < 8; ++i) {
      const int tt = t0 + 8 + i;
      fnxt[i] = (tt < LSEQ) ? feats[tt * NTAG + nt] : 0.0f;
    }
#pragma unroll
    for (int i = 0; i < 8; ++i) {
      const int t = t0 + i;
      float b0 = -3.4e38f, b1 = -3.4e38f, b2 = -3.4e38f, b3 = -3.4e38f;
      int i0 = 0, i1 = 0, i2 = 0, i3 = 0;
#define CAND(p, B, I)                                                     \
  {                                                                       \
    const float fvp = __builtin_bit_cast(                                 \
        float, __builtin_amdgcn_readlane(__builtin_bit_cast(int, fv), (p))); \
    const float v = fvp + tr[p];                                          \
    if (v > B) {                                                          \
      B = v;                                                              \
      I = (p);                                                            \
    }                                                                     \
  }
      CAND(0, b0, i0) CAND(1, b0, i0) CAND(2, b0, i0) CAND(3, b0, i0)
      CAND(4, b0, i0)
      CAND(5, b1, i1) CAND(6, b1, i1) CAND(7, b1, i1) CAND(8, b1, i1)
      CAND(9, b1, i1)
      CAND(10, b2, i2) CAND(11, b2, i2) CAND(12, b2, i2) CAND(13, b2, i2)
      CAND(14, b2, i2)
      CAND(15, b3, i3) CAND(16, b3, i3) CAND(17, b3, i3) CAND(18, b3, i3)
      CAND(19, b3, i3)
#undef CAND
      float best = b0;
      int bi = i0;
      if (b1 > best) { best = b1; bi = i1; }
      if (b2 > best) { best = b2; bi = i2; }
      if (b3 > best) { best = b3; bi = i3; }
      fv = best + fcur[i];
      if (lane < NTAG) bp[t * NTAG + lane] = (unsigned char)bi;
    }
#pragma unroll
    for (int i = 0; i < 8; ++i) fcur[i] = fnxt[i];
  }

  if (lane < NTAG) termb[lane] = fv + trans[TAG_STOP * NTAG + lane];
  __syncthreads();
  if (lane == 0) {
    float best = termb[0];
    int bi = 0;
#pragma unroll
    for (int p = 1; p < NTAG; ++p) {
      const float v = termb[p];
      if (v > best) {
        best = v;
        bi = p;
      }
    }
    out[0] = best;
    bnd[63] = (unsigned char)bi;
  }
  __syncthreads();

  // compose per-chunk backpointer maps (64 steps each) in parallel
  {
    const int c = lane;
    int m[NTAG];
#pragma unroll
    for (int e = 0; e < NTAG; ++e) m[e] = e;
    for (int s = 63; s >= 0; --s) {
      const int base = (c * 64 + s) * NTAG;
#pragma unroll
      for (int e = 0; e < NTAG; ++e) m[e] = bp[base + m[e]];
    }
#pragma unroll
    for (int e = 0; e < NTAG; ++e) fmap[c][e] = (unsigned char)m[e];
  }
  __syncthreads();
  if (lane == 0) {
    for (int cc = 63; cc >= 1; --cc) bnd[cc - 1] = fmap[cc][bnd[cc]];
  }
  __syncthreads();
  // per-lane backtrack inside own chunk
  {
    const int c = lane;
    int cur = bnd[c];
    out[1 + c * 64 + 63] = (float)cur;
    for (int s2 = 63; s2 >= 1; --s2) {
      cur = bp[(c * 64 + s2) * NTAG + cur];
      out[1 + c * 64 + s2 - 1] = (float)cur;
    }
  }
}

extern "C" void kernel_launch(void* const* d_in, const int* in_sizes, int n_in,
                              void* d_out, int out_size, void* d_ws,
                              size_t ws_size, hipStream_t stream) {
  const int* sentence = (const int*)d_in[0];
  const float* etab = (const float*)d_in[1];
  const float* Wihf = (const float*)d_in[2];
  const float* Whhf = (const float*)d_in[3];
  const float* bihf = (const float*)d_in[4];
  const float* bhhf = (const float*)d_in[5];
  const float* Wihb = (const float*)d_in[6];
  const float* Whhb = (const float*)d_in[7];
  const float* bihb = (const float*)d_in[8];
  const float* bhhb = (const float*)d_in[9];
  const float* Wout = (const float*)d_in[10];
  const float* bout = (const float*)d_in[11];
  const float* trans = (const float*)d_in[12];
  const float* h0 = (const float*)d_in[13];
  const float* c0 = (const float*)d_in[14];

  float* ws = (float*)d_ws;
  float* xpf = ws;
  float* xpb = xpf + (size_t)LSEQ * GD;
  float* hfp = xpb + (size_t)LSEQ * GD;
  float* hbp = hfp + (size_t)LSEQ * HD;
  float* feats = hbp + (size_t)LSEQ * HD;
  float* outp = (float*)d_out;

  xp_gemm<<<dim3(GD / 64, LSEQ / 64, 2), 256, 0, stream>>>(
      sentence, etab, Wihf, Wihb, bihf, bhhf, bihb, bhhb, xpf, xpb);
  lstm_scan<<<2, 1024, 0, stream>>>(Whhf, Whhb, xpf, xpb, h0, c0, hfp, hbp);
  feats_kernel<<<LSEQ / 32, 256, 0, stream>>>(hfp, hbp, Wout, bout, feats);
  viterbi_kernel<<<1, 64, 0, stream>>>(feats, trans, outp);
}

// Round 14
// 4415.684 us; speedup vs baseline: 1.5737x; 1.2080x over previous
//
#include <hip/hip_runtime.h>
#include <hip/hip_fp16.h>

#define LSEQ 4096
#define HD 256
#define GD 1024
#define NTAG 20
#define TAG_START 1
#define TAG_STOP 0
#define NEGV -10000.0f

#define CH 16
#define NCH 256  // LSEQ / CH

typedef unsigned int u32;

#define USE_SDOT4 1
#if defined(__has_builtin)
#if !__has_builtin(__builtin_amdgcn_sdot4)
#undef USE_SDOT4
#define USE_SDOT4 0
#endif
#endif

__device__ __forceinline__ int sdot4(u32 a, u32 b, int c) {
#if USE_SDOT4
  return __builtin_amdgcn_sdot4((int)a, (int)b, c, false);
#else
  int r = c;
  r += ((int)(a << 24) >> 24) * ((int)(b << 24) >> 24);
  r += ((int)(a << 16) >> 24) * ((int)(b << 16) >> 24);
  r += ((int)(a << 8) >> 24) * ((int)(b << 8) >> 24);
  r += ((int)a >> 24) * ((int)b >> 24);
  return r;
#endif
}

// quantize 4 consecutive f32 weights to i8 at scale 2048, pack little-endian
__device__ __forceinline__ u32 q4(const float* w) {
  const int b0 = (int)rintf(fminf(fmaxf(w[0] * 2048.f, -127.f), 127.f));
  const int b1 = (int)rintf(fminf(fmaxf(w[1] * 2048.f, -127.f), 127.f));
  const int b2 = (int)rintf(fminf(fmaxf(w[2] * 2048.f, -127.f), 127.f));
  const int b3 = (int)rintf(fminf(fmaxf(w[3] * 2048.f, -127.f), 127.f));
  return (u32)(b0 & 255) | ((u32)(b1 & 255) << 8) | ((u32)(b2 & 255) << 16) |
         ((u32)(b3 & 255) << 24);
}

__device__ __forceinline__ float rlf(float x, int l) {
  return __builtin_bit_cast(
      float, __builtin_amdgcn_readlane(__builtin_bit_cast(int, x), l));
}

__device__ __forceinline__ float fsigm(float x) {
  return 1.0f / (1.0f + __expf(-x));
}
__device__ __forceinline__ float ftanh(float x) {
  float t = __expf(-2.0f * fabsf(x));
  float r = (1.0f - t) / (1.0f + t);
  return x < 0.0f ? -r : r;
}

// ---------------- K1: xp = emb @ W_ih^T + biases, gather fused, both dirs ----
__global__ __launch_bounds__(256) void xp_gemm(
    const int* __restrict__ sent, const float* __restrict__ etab,
    const float* __restrict__ Wf, const float* __restrict__ Wb,
    const float* __restrict__ bihf, const float* __restrict__ bhhf,
    const float* __restrict__ bihb, const float* __restrict__ bhhb,
    float* __restrict__ xpf, float* __restrict__ xpb) {
  const int dir = blockIdx.z;
  const float* __restrict__ W = dir ? Wb : Wf;
  const float* __restrict__ b1 = dir ? bihb : bihf;
  const float* __restrict__ b2 = dir ? bhhb : bhhf;
  float* __restrict__ out = dir ? xpb : xpf;
  __shared__ float As[32][64];
  __shared__ float Bs[32][64];
  const int bm = blockIdx.y * 64;
  const int bn = blockIdx.x * 64;
  const int tid = threadIdx.x;
  const int tx = tid & 15, ty = tid >> 4;
  const int lm = tid & 63, lk = tid >> 6;  // loader: row lm, k-quad lk
  const size_t arow = (size_t)sent[bm + lm] * HD;  // gather fused
  float acc[4][4];
#pragma unroll
  for (int i = 0; i < 4; ++i)
#pragma unroll
    for (int j = 0; j < 4; ++j) acc[i][j] = 0.0f;

  for (int k0 = 0; k0 < HD; k0 += 32) {
    float4 a0 = *(const float4*)&etab[arow + k0 + lk * 4];
    float4 a1 = *(const float4*)&etab[arow + k0 + 16 + lk * 4];
    float4 c0 = *(const float4*)&W[(bn + lm) * HD + k0 + lk * 4];
    float4 c1 = *(const float4*)&W[(bn + lm) * HD + k0 + 16 + lk * 4];
    __syncthreads();
    As[lk * 4 + 0][lm] = a0.x;
    As[lk * 4 + 1][lm] = a0.y;
    As[lk * 4 + 2][lm] = a0.z;
    As[lk * 4 + 3][lm] = a0.w;
    As[16 + lk * 4 + 0][lm] = a1.x;
    As[16 + lk * 4 + 1][lm] = a1.y;
    As[16 + lk * 4 + 2][lm] = a1.z;
    As[16 + lk * 4 + 3][lm] = a1.w;
    Bs[lk * 4 + 0][lm] = c0.x;
    Bs[lk * 4 + 1][lm] = c0.y;
    Bs[lk * 4 + 2][lm] = c0.z;
    Bs[lk * 4 + 3][lm] = c0.w;
    Bs[16 + lk * 4 + 0][lm] = c1.x;
    Bs[16 + lk * 4 + 1][lm] = c1.y;
    Bs[16 + lk * 4 + 2][lm] = c1.z;
    Bs[16 + lk * 4 + 3][lm] = c1.w;
    __syncthreads();
#pragma unroll
    for (int k = 0; k < 32; ++k) {
      float4 av = *(const float4*)&As[k][ty * 4];
      float4 bv = *(const float4*)&Bs[k][tx * 4];
      float am[4] = {av.x, av.y, av.z, av.w};
      float bn_[4] = {bv.x, bv.y, bv.z, bv.w};
#pragma unroll
      for (int i = 0; i < 4; ++i)
#pragma unroll
        for (int j = 0; j < 4; ++j) acc[i][j] += am[i] * bn_[j];
    }
  }
#pragma unroll
  for (int i = 0; i < 4; ++i) {
    const int m = bm + ty * 4 + i;
#pragma unroll
    for (int j = 0; j < 4; ++j) {
      const int n = bn + tx * 4 + j;
      out[m * GD + n] = acc[i][j] + b1[n] + b2[n];
    }
  }
}

// ---------------- K2: BiLSTM scan, int8, ALL weights register-resident --------
// (R10 structure, best measured: 4240 us. Frozen.)
__global__ __launch_bounds__(1024) void lstm_scan(
    const float* __restrict__ Whhf, const float* __restrict__ Whhb,
    const float* __restrict__ xpf, const float* __restrict__ xpb,
    const float* __restrict__ h0, const float* __restrict__ c0,
    float* __restrict__ hf, float* __restrict__ hb) {
  const int dir = blockIdx.x;
  const float* __restrict__ Whh = dir ? Whhb : Whhf;
  const float* __restrict__ xp = dir ? xpb : xpf;
  float* __restrict__ hout = dir ? hb : hf;
  const int t = threadIdx.x;  // z-row 0..1023

  __shared__ __align__(16) u32 hq[2][64];  // packed i8 h, ping-pong (512 B)
  __shared__ float zbuf[GD];               // 4 KB

  uint4 wA0, wA1, wA2, wA3, wA4, wA5, wA6, wA7;
  uint4 wA8, wA9, wA10, wA11, wA12, wA13, wA14, wA15;
#define LW(j)                                           \
  {                                                     \
    const float* s0 = &Whh[(size_t)t * HD + (j) * 16];  \
    wA##j.x = q4(s0);                                   \
    wA##j.y = q4(s0 + 4);                               \
    wA##j.z = q4(s0 + 8);                               \
    wA##j.w = q4(s0 + 12);                              \
  }
  LW(0) LW(1) LW(2) LW(3) LW(4) LW(5) LW(6) LW(7)
  LW(8) LW(9) LW(10) LW(11) LW(12) LW(13) LW(14) LW(15)
#undef LW

  float cst = 0.0f;
  if (t < HD) {
    cst = c0[dir * HD + t];
    const int hq0 =
        (int)rintf(fminf(fmaxf(h0[dir * HD + t] * 16.f, -127.f), 127.f));
    ((unsigned char*)&hq[0][0])[t] = (unsigned char)(hq0 & 255);
  }
  __syncthreads();

  for (int s = 0; s < LSEQ; ++s) {
    const int tt = dir ? (LSEQ - 1 - s) : s;
    const int par = s & 1;
    const float dq =
        (s == 0) ? (1.f / (2048.f * 16.f)) : (1.f / (2048.f * 127.f));
    float xg0 = 0.f, xg1 = 0.f, xg2 = 0.f, xg3 = 0.f;
    if (t < HD) {
      const float* xr = &xp[(size_t)tt * GD + t];
      xg0 = xr[0];
      xg1 = xr[HD];
      xg2 = xr[2 * HD];
      xg3 = xr[3 * HD];
    }
    const uint4* hq4 = (const uint4*)&hq[par][0];
    int acc = 0;
#define MV(j)                         \
  {                                   \
    const uint4 hv = hq4[j];          \
    acc = sdot4(wA##j.x, hv.x, acc);  \
    acc = sdot4(wA##j.y, hv.y, acc);  \
    acc = sdot4(wA##j.z, hv.z, acc);  \
    acc = sdot4(wA##j.w, hv.w, acc);  \
  }
    MV(0) MV(1) MV(2) MV(3) MV(4) MV(5) MV(6) MV(7)
    MV(8) MV(9) MV(10) MV(11) MV(12) MV(13) MV(14) MV(15)
#undef MV
    zbuf[t] = (float)acc * dq;
    __syncthreads();  // A: z complete
    if (t < HD) {
      const float zi = zbuf[t] + xg0;
      const float zf = zbuf[HD + t] + xg1;
      const float zg = zbuf[2 * HD + t] + xg2;
      const float zo = zbuf[3 * HD + t] + xg3;
      const float ig = fsigm(zi), fg = fsigm(zf), gg = ftanh(zg),
                  og = fsigm(zo);
      const float cv = fg * cst + ig * gg;
      cst = cv;
      const float hv = og * ftanh(cv);
      hout[(size_t)tt * HD + t] = hv;
      const int hqv = (int)rintf(fminf(fmaxf(hv * 127.f, -127.f), 127.f));
      ((unsigned char*)&hq[par ^ 1][0])[t] = (unsigned char)(hqv & 255);
    }
    __syncthreads();  // B: next-step h ready
  }
}

// ---------------- K3: feats = [hf|hb] @ W_out^T + b_out ----------------
__global__ __launch_bounds__(256) void feats_kernel(
    const float* __restrict__ hf, const float* __restrict__ hb,
    const float* __restrict__ Wout, const float* __restrict__ bout,
    float* __restrict__ feats) {
  __shared__ float Ws[NTAG][520];
  __shared__ float bs[NTAG];
  const int tid = threadIdx.x;
  for (int i = tid; i < NTAG * 512; i += 256) Ws[i / 512][i % 512] = Wout[i];
  if (tid < NTAG) bs[tid] = bout[tid];
  __syncthreads();
  const int t0 = blockIdx.x * 32;
  for (int idx = tid; idx < 32 * NTAG; idx += 256) {
    const int t = t0 + idx / NTAG;
    const int tag = idx % NTAG;
    const float* __restrict__ hfr = &hf[t * HD];
    const float* __restrict__ hbr = &hb[t * HD];
    float s = bs[tag];
#pragma unroll 8
    for (int k = 0; k < HD; ++k) {
      s += hfr[k] * Ws[tag][k];
      s += hbr[k] * Ws[tag][HD + k];
    }
    feats[t * NTAG + tag] = s;
  }
}

// ---------------- K4a: per-chunk max-plus matrix (parallel over 256 chunks) --
// Block c composes steps [c*16, c*16+16) into M_c[n][p] (20x20, max-plus).
// Lane p holds column p: m[q] = M[q][p] in 20 regs (all indices static).
__global__ __launch_bounds__(64) void vit_chunkM(
    const float* __restrict__ feats, const float* __restrict__ trans,
    float* __restrict__ M) {
  const int c = blockIdx.x;
  const int lane = threadIdx.x;
  const int p = lane < NTAG ? lane : 0;
  __shared__ float trL[NTAG * NTAG];
  for (int i = lane; i < NTAG * NTAG; i += 64) trL[i] = trans[i];
  const int t0 = c * CH;
  float ft_cur = feats[(size_t)t0 * NTAG + p];        // feat[t0][lane]
  float ft_next = feats[(size_t)(t0 + 1) * NTAG + p];  // prefetch
  __syncthreads();
  float m[NTAG];
#pragma unroll
  for (int n = 0; n < NTAG; ++n) m[n] = trL[n * NTAG + p] + rlf(ft_cur, n);
  for (int s = 1; s < CH; ++s) {
    ft_cur = ft_next;
    if (s + 1 < CH) ft_next = feats[(size_t)(t0 + s + 1) * NTAG + p];
    float nm[NTAG];
#pragma unroll
    for (int n = 0; n < NTAG; ++n) {
      float b = trL[n * NTAG + 0] + m[0];
#pragma unroll
      for (int qq = 1; qq < NTAG; ++qq)
        b = fmaxf(b, trL[n * NTAG + qq] + m[qq]);
      nm[n] = b + rlf(ft_cur, n);
    }
#pragma unroll
    for (int n = 0; n < NTAG; ++n) m[n] = nm[n];
  }
  if (lane < NTAG) {
#pragma unroll
    for (int qq = 0; qq < NTAG; ++qq)
      M[(size_t)c * (NTAG * NTAG) + qq * NTAG + lane] = m[qq];
  }
}

// ---------------- K4b: serial compose over 256 chunk matrices (1 wave) -------
__global__ __launch_bounds__(64) void vit_compose(
    const float* __restrict__ M, const float* __restrict__ trans,
    float* __restrict__ fvst, float* __restrict__ out, int* __restrict__ blp) {
  const int lane = threadIdx.x;
  const int n = lane < NTAG ? lane : 0;
  float fv = (lane == TAG_START) ? 0.0f : NEGV;
  // prefetch row n of M_0
  const float* Mr = M + (size_t)n * NTAG;
  float4 r0 = *(const float4*)(Mr + 0), r1 = *(const float4*)(Mr + 4);
  float4 r2 = *(const float4*)(Mr + 8), r3 = *(const float4*)(Mr + 12);
  float4 r4 = *(const float4*)(Mr + 16);
  for (int c = 0; c < NCH; ++c) {
    if (lane < NTAG) fvst[c * NTAG + lane] = fv;
    const float4 c0 = r0, c1 = r1, c2 = r2, c3 = r3, c4 = r4;
    if (c + 1 < NCH) {
      const float* Mn = M + (size_t)(c + 1) * (NTAG * NTAG) + n * NTAG;
      r0 = *(const float4*)(Mn + 0);
      r1 = *(const float4*)(Mn + 4);
      r2 = *(const float4*)(Mn + 8);
      r3 = *(const float4*)(Mn + 12);
      r4 = *(const float4*)(Mn + 16);
    }
    const float mr[NTAG] = {c0.x, c0.y, c0.z, c0.w, c1.x, c1.y, c1.z,
                            c1.w, c2.x, c2.y, c2.z, c2.w, c3.x, c3.y,
                            c3.z, c3.w, c4.x, c4.y, c4.z, c4.w};
    float b = mr[0] + rlf(fv, 0);
#pragma unroll
    for (int pp = 1; pp < NTAG; ++pp) b = fmaxf(b, mr[pp] + rlf(fv, pp));
    fv = b;
  }
  // terminal: term[n] = fv[n] + trans[STOP][n]
  const float term = fv + trans[TAG_STOP * NTAG + n];
  float bb = rlf(term, 0);
  int bi = 0;
#pragma unroll
  for (int pp = 1; pp < NTAG; ++pp) {
    const float v = rlf(term, pp);
    if (v > bb) {
      bb = v;
      bi = pp;
    }
  }
  if (lane == 0) {
    out[0] = bb;
    *blp = bi;
  }
}

// ---------------- K4c: per-chunk replay (bp + candidate paths + fmap) --------
__global__ __launch_bounds__(64) void vit_replay(
    const float* __restrict__ feats, const float* __restrict__ trans,
    const float* __restrict__ fvst, unsigned char* __restrict__ pcand,
    unsigned char* __restrict__ fmap) {
  const int c = blockIdx.x;
  const int lane = threadIdx.x;
  const int nt = lane < NTAG ? lane : 0;
  __shared__ unsigned char bpL[CH][NTAG];
  float tr[NTAG];
#pragma unroll
  for (int p = 0; p < NTAG; ++p) tr[p] = trans[nt * NTAG + p];
  float fv = (lane < NTAG) ? fvst[c * NTAG + lane] : NEGV;
  const int t0 = c * CH;
  float fc_cur = feats[(size_t)t0 * NTAG + nt];
  float fc_next = feats[(size_t)(t0 + 1) * NTAG + nt];
  for (int s = 0; s < CH; ++s) {
    float b0 = -3.4e38f, b1 = -3.4e38f, b2 = -3.4e38f, b3 = -3.4e38f;
    int i0 = 0, i1 = 0, i2 = 0, i3 = 0;
#define CAND(p, B, I)                 \
  {                                   \
    const float fvp = rlf(fv, (p));   \
    const float v = fvp + tr[p];      \
    if (v > B) {                      \
      B = v;                          \
      I = (p);                        \
    }                                 \
  }
    CAND(0, b0, i0) CAND(1, b0, i0) CAND(2, b0, i0) CAND(3, b0, i0)
    CAND(4, b0, i0)
    CAND(5, b1, i1) CAND(6, b1, i1) CAND(7, b1, i1) CAND(8, b1, i1)
    CAND(9, b1, i1)
    CAND(10, b2, i2) CAND(11, b2, i2) CAND(12, b2, i2) CAND(13, b2, i2)
    CAND(14, b2, i2)
    CAND(15, b3, i3) CAND(16, b3, i3) CAND(17, b3, i3) CAND(18, b3, i3)
    CAND(19, b3, i3)
#undef CAND
    float best = b0;
    int bi = i0;
    if (b1 > best) { best = b1; bi = i1; }
    if (b2 > best) { best = b2; bi = i2; }
    if (b3 > best) { best = b3; bi = i3; }
    fv = best + fc_cur;
    if (lane < NTAG) bpL[s][lane] = (unsigned char)bi;
    fc_cur = fc_next;
    if (s + 2 < CH) fc_next = feats[(size_t)(t0 + s + 2) * NTAG + nt];
  }
  __syncthreads();
  if (lane < NTAG) {
    unsigned char loc[CH];
    int cur = lane;
    loc[CH - 1] = (unsigned char)cur;
#pragma unroll
    for (int s2 = CH - 1; s2 >= 1; --s2) {
      cur = bpL[s2][cur];
      loc[s2 - 1] = (unsigned char)cur;
    }
    fmap[c * NTAG + lane] = bpL[0][cur];
    u32 w0 = (u32)loc[0] | ((u32)loc[1] << 8) | ((u32)loc[2] << 16) |
             ((u32)loc[3] << 24);
    u32 w1 = (u32)loc[4] | ((u32)loc[5] << 8) | ((u32)loc[6] << 16) |
             ((u32)loc[7] << 24);
    u32 w2 = (u32)loc[8] | ((u32)loc[9] << 8) | ((u32)loc[10] << 16) |
             ((u32)loc[11] << 24);
    u32 w3 = (u32)loc[12] | ((u32)loc[13] << 8) | ((u32)loc[14] << 16) |
             ((u32)loc[15] << 24);
    uint4 w;
    w.x = w0;
    w.y = w1;
    w.z = w2;
    w.w = w3;
    *(uint4*)&pcand[((size_t)c * NTAG + lane) * CH] = w;
  }
}

// ---------------- K4d: chain fmaps + emit path ----------------
__global__ __launch_bounds__(64) void vit_final(
    const unsigned char* __restrict__ pcand,
    const unsigned char* __restrict__ fmap, const int* __restrict__ blp,
    float* __restrict__ out) {
  __shared__ unsigned char fm[NCH * NTAG];
  __shared__ short bnd[NCH];
  const int lane = threadIdx.x;
  for (int i = lane; i < NCH * NTAG; i += 64) fm[i] = fmap[i];
  __syncthreads();
  if (lane == 0) {
    int cur = *blp;
    bnd[NCH - 1] = (short)cur;
    for (int c = NCH - 1; c >= 1; --c) {
      cur = fm[c * NTAG + cur];
      bnd[c - 1] = (short)cur;
    }
  }
  __syncthreads();
  for (int cc = lane; cc < NCH; cc += 64) {
    const int e = bnd[cc];
    const uint4 w = *(const uint4*)&pcand[((size_t)cc * NTAG + e) * CH];
    const u32 ws[4] = {w.x, w.y, w.z, w.w};
#pragma unroll
    for (int j = 0; j < 4; ++j) {
#pragma unroll
      for (int b = 0; b < 4; ++b) {
        out[1 + cc * CH + j * 4 + b] = (float)((ws[j] >> (8 * b)) & 255u);
      }
    }
  }
}

extern "C" void kernel_launch(void* const* d_in, const int* in_sizes, int n_in,
                              void* d_out, int out_size, void* d_ws,
                              size_t ws_size, hipStream_t stream) {
  const int* sentence = (const int*)d_in[0];
  const float* etab = (const float*)d_in[1];
  const float* Wihf = (const float*)d_in[2];
  const float* Whhf = (const float*)d_in[3];
  const float* bihf = (const float*)d_in[4];
  const float* bhhf = (const float*)d_in[5];
  const float* Wihb = (const float*)d_in[6];
  const float* Whhb = (const float*)d_in[7];
  const float* bihb = (const float*)d_in[8];
  const float* bhhb = (const float*)d_in[9];
  const float* Wout = (const float*)d_in[10];
  const float* bout = (const float*)d_in[11];
  const float* trans = (const float*)d_in[12];
  const float* h0 = (const float*)d_in[13];
  const float* c0 = (const float*)d_in[14];

  float* ws = (float*)d_ws;
  float* xpf = ws;
  float* xpb = xpf + (size_t)LSEQ * GD;
  float* hfp = xpb + (size_t)LSEQ * GD;
  float* hbp = hfp + (size_t)LSEQ * HD;
  float* feats = hbp + (size_t)LSEQ * HD;
  float* Mv = feats + (size_t)LSEQ * NTAG;          // 256*400 floats
  float* fvst = Mv + (size_t)NCH * NTAG * NTAG;     // 256*20 floats
  int* blp = (int*)(fvst + (size_t)NCH * NTAG);     // 4 ints reserved
  unsigned char* pcand = (unsigned char*)(blp + 4); // 256*20*16 bytes
  unsigned char* fmapb = pcand + (size_t)NCH * NTAG * CH;  // 256*20 bytes
  float* outp = (float*)d_out;

  xp_gemm<<<dim3(GD / 64, LSEQ / 64, 2), 256, 0, stream>>>(
      sentence, etab, Wihf, Wihb, bihf, bhhf, bihb, bhhb, xpf, xpb);
  lstm_scan<<<2, 1024, 0, stream>>>(Whhf, Whhb, xpf, xpb, h0, c0, hfp, hbp);
  feats_kernel<<<LSEQ / 32, 256, 0, stream>>>(hfp, hbp, Wout, bout, feats);
  vit_chunkM<<<NCH, 64, 0, stream>>>(feats, trans, Mv);
  vit_compose<<<1, 64, 0, stream>>>(Mv, trans, fvst, outp, blp);
  vit_replay<<<NCH, 64, 0, stream>>>(feats, trans, fvst, pcand, fmapb);
  vit_final<<<1, 64, 0, stream>>>(pcand, fmapb, blp, outp);
}

// Round 15
// 4123.822 us; speedup vs baseline: 1.6850x; 1.0708x over previous
//
#include <hip/hip_runtime.h>
#include <hip/hip_fp16.h>

#define LSEQ 4096
#define HD 256
#define GD 1024
#define NTAG 20
#define TAG_START 1
#define TAG_STOP 0
#define NEGV -10000.0f

#define CH 16
#define NCH 256  // LSEQ / CH

typedef unsigned int u32;

#define USE_SDOT4 1
#if defined(__has_builtin)
#if !__has_builtin(__builtin_amdgcn_sdot4)
#undef USE_SDOT4
#define USE_SDOT4 0
#endif
#endif

__device__ __forceinline__ int sdot4(u32 a, u32 b, int c) {
#if USE_SDOT4
  return __builtin_amdgcn_sdot4((int)a, (int)b, c, false);
#else
  int r = c;
  r += ((int)(a << 24) >> 24) * ((int)(b << 24) >> 24);
  r += ((int)(a << 16) >> 24) * ((int)(b << 16) >> 24);
  r += ((int)(a << 8) >> 24) * ((int)(b << 8) >> 24);
  r += ((int)a >> 24) * ((int)b >> 24);
  return r;
#endif
}

// quantize 4 consecutive f32 weights to i8 at scale 2048, pack little-endian
__device__ __forceinline__ u32 q4(const float* w) {
  const int b0 = (int)rintf(fminf(fmaxf(w[0] * 2048.f, -127.f), 127.f));
  const int b1 = (int)rintf(fminf(fmaxf(w[1] * 2048.f, -127.f), 127.f));
  const int b2 = (int)rintf(fminf(fmaxf(w[2] * 2048.f, -127.f), 127.f));
  const int b3 = (int)rintf(fminf(fmaxf(w[3] * 2048.f, -127.f), 127.f));
  return (u32)(b0 & 255) | ((u32)(b1 & 255) << 8) | ((u32)(b2 & 255) << 16) |
         ((u32)(b3 & 255) << 24);
}

__device__ __forceinline__ float rlf(float x, int l) {
  return __builtin_bit_cast(
      float, __builtin_amdgcn_readlane(__builtin_bit_cast(int, x), l));
}

__device__ __forceinline__ float fsigm(float x) {
  return 1.0f / (1.0f + __expf(-x));
}
__device__ __forceinline__ float ftanh(float x) {
  float t = __expf(-2.0f * fabsf(x));
  float r = (1.0f - t) / (1.0f + t);
  return x < 0.0f ? -r : r;
}

// ---------------- K1: xp = emb @ W_ih^T + biases, gather fused, both dirs ----
__global__ __launch_bounds__(256) void xp_gemm(
    const int* __restrict__ sent, const float* __restrict__ etab,
    const float* __restrict__ Wf, const float* __restrict__ Wb,
    const float* __restrict__ bihf, const float* __restrict__ bhhf,
    const float* __restrict__ bihb, const float* __restrict__ bhhb,
    float* __restrict__ xpf, float* __restrict__ xpb) {
  const int dir = blockIdx.z;
  const float* __restrict__ W = dir ? Wb : Wf;
  const float* __restrict__ b1 = dir ? bihb : bihf;
  const float* __restrict__ b2 = dir ? bhhb : bhhf;
  float* __restrict__ out = dir ? xpb : xpf;
  __shared__ float As[32][64];
  __shared__ float Bs[32][64];
  const int bm = blockIdx.y * 64;
  const int bn = blockIdx.x * 64;
  const int tid = threadIdx.x;
  const int tx = tid & 15, ty = tid >> 4;
  const int lm = tid & 63, lk = tid >> 6;  // loader: row lm, k-quad lk
  const size_t arow = (size_t)sent[bm + lm] * HD;  // gather fused
  float acc[4][4];
#pragma unroll
  for (int i = 0; i < 4; ++i)
#pragma unroll
    for (int j = 0; j < 4; ++j) acc[i][j] = 0.0f;

  for (int k0 = 0; k0 < HD; k0 += 32) {
    float4 a0 = *(const float4*)&etab[arow + k0 + lk * 4];
    float4 a1 = *(const float4*)&etab[arow + k0 + 16 + lk * 4];
    float4 c0 = *(const float4*)&W[(bn + lm) * HD + k0 + lk * 4];
    float4 c1 = *(const float4*)&W[(bn + lm) * HD + k0 + 16 + lk * 4];
    __syncthreads();
    As[lk * 4 + 0][lm] = a0.x;
    As[lk * 4 + 1][lm] = a0.y;
    As[lk * 4 + 2][lm] = a0.z;
    As[lk * 4 + 3][lm] = a0.w;
    As[16 + lk * 4 + 0][lm] = a1.x;
    As[16 + lk * 4 + 1][lm] = a1.y;
    As[16 + lk * 4 + 2][lm] = a1.z;
    As[16 + lk * 4 + 3][lm] = a1.w;
    Bs[lk * 4 + 0][lm] = c0.x;
    Bs[lk * 4 + 1][lm] = c0.y;
    Bs[lk * 4 + 2][lm] = c0.z;
    Bs[lk * 4 + 3][lm] = c0.w;
    Bs[16 + lk * 4 + 0][lm] = c1.x;
    Bs[16 + lk * 4 + 1][lm] = c1.y;
    Bs[16 + lk * 4 + 2][lm] = c1.z;
    Bs[16 + lk * 4 + 3][lm] = c1.w;
    __syncthreads();
#pragma unroll
    for (int k = 0; k < 32; ++k) {
      float4 av = *(const float4*)&As[k][ty * 4];
      float4 bv = *(const float4*)&Bs[k][tx * 4];
      float am[4] = {av.x, av.y, av.z, av.w};
      float bn_[4] = {bv.x, bv.y, bv.z, bv.w};
#pragma unroll
      for (int i = 0; i < 4; ++i)
#pragma unroll
        for (int j = 0; j < 4; ++j) acc[i][j] += am[i] * bn_[j];
    }
  }
#pragma unroll
  for (int i = 0; i < 4; ++i) {
    const int m = bm + ty * 4 + i;
#pragma unroll
    for (int j = 0; j < 4; ++j) {
      const int n = bn + tx * 4 + j;
      out[m * GD + n] = acc[i][j] + b1[n] + b2[n];
    }
  }
}

// ---------------- K2: BiLSTM scan, int8 resident, 2-way k-split --------------
// One WG (1024 thr, 16 waves) per direction. Thread t -> half g=t>>9, u=t&511:
// owns rows {u, u+512} restricted to k-half [g*128, g*128+128). Weights: 16
// named uint4 = 64 regs (proven R10 allocation). Each thread reads only 8
// broadcast b128 of h (halves LDS b128 count: 256->128 per step per CU).
// Integer partials -> zpart[g][row] (lane-contiguous conflict-free writes);
// gate phase sums the two int halves -- numerics identical to R10.
__global__ __launch_bounds__(1024) void lstm_scan(
    const float* __restrict__ Whhf, const float* __restrict__ Whhb,
    const float* __restrict__ xpf, const float* __restrict__ xpb,
    const float* __restrict__ h0, const float* __restrict__ c0,
    float* __restrict__ hf, float* __restrict__ hb) {
  const int dir = blockIdx.x;
  const float* __restrict__ Whh = dir ? Whhb : Whhf;
  const float* __restrict__ xp = dir ? xpb : xpf;
  float* __restrict__ hout = dir ? hb : hf;
  const int t = threadIdx.x;
  const int g = t >> 9;   // k-half index (0: k<128, 1: k>=128)
  const int u = t & 511;  // row base: rows u and u+512
  const int kb = g * 128; // k start (i8 elements)

  __shared__ __align__(16) u32 hq[2][64];  // packed i8 h, ping-pong (512 B)
  __shared__ int zpart[2][GD];             // 8 KB int partials [half][row]

  // resident weights: rows u and u+512, k-half g -> 16 named uint4 (64 VGPRs)
  uint4 wA0, wA1, wA2, wA3, wA4, wA5, wA6, wA7;
  uint4 wB0, wB1, wB2, wB3, wB4, wB5, wB6, wB7;
#define LW(j)                                                     \
  {                                                               \
    const float* s0 = &Whh[(size_t)u * HD + kb + (j) * 16];       \
    wA##j.x = q4(s0);                                             \
    wA##j.y = q4(s0 + 4);                                         \
    wA##j.z = q4(s0 + 8);                                         \
    wA##j.w = q4(s0 + 12);                                        \
    const float* s1 = &Whh[(size_t)(u + 512) * HD + kb + (j) * 16]; \
    wB##j.x = q4(s1);                                             \
    wB##j.y = q4(s1 + 4);                                         \
    wB##j.z = q4(s1 + 8);                                         \
    wB##j.w = q4(s1 + 12);                                        \
  }
  LW(0) LW(1) LW(2) LW(3) LW(4) LW(5) LW(6) LW(7)
#undef LW

  float cst = 0.0f;
  if (t < HD) {
    cst = c0[dir * HD + t];
    const int hq0 =
        (int)rintf(fminf(fmaxf(h0[dir * HD + t] * 16.f, -127.f), 127.f));
    ((unsigned char*)&hq[0][0])[t] = (unsigned char)(hq0 & 255);
  }
  __syncthreads();

  for (int s = 0; s < LSEQ; ++s) {
    const int tt = dir ? (LSEQ - 1 - s) : s;
    const int par = s & 1;
    const float dq =
        (s == 0) ? (1.f / (2048.f * 16.f)) : (1.f / (2048.f * 127.f));
    // xp prefetch for the gate phase (hidden under the matvec)
    float xg0 = 0.f, xg1 = 0.f, xg2 = 0.f, xg3 = 0.f;
    if (t < HD) {
      const float* xr = &xp[(size_t)tt * GD + t];
      xg0 = xr[0];
      xg1 = xr[HD];
      xg2 = xr[2 * HD];
      xg3 = xr[3 * HD];
    }
    // matvec: 8 broadcast b128 reads of this thread's h-half, 64 sdot4
    const uint4* hq4 = (const uint4*)&hq[par][g * 32];
    int accA = 0, accB = 0;
#define MV(j)                          \
  {                                    \
    const uint4 hv = hq4[j];           \
    accA = sdot4(wA##j.x, hv.x, accA); \
    accA = sdot4(wA##j.y, hv.y, accA); \
    accA = sdot4(wA##j.z, hv.z, accA); \
    accA = sdot4(wA##j.w, hv.w, accA); \
    accB = sdot4(wB##j.x, hv.x, accB); \
    accB = sdot4(wB##j.y, hv.y, accB); \
    accB = sdot4(wB##j.z, hv.z, accB); \
    accB = sdot4(wB##j.w, hv.w, accB); \
  }
    MV(0) MV(1) MV(2) MV(3) MV(4) MV(5) MV(6) MV(7)
#undef MV
    zpart[g][u] = accA;        // lane-contiguous, conflict-free
    zpart[g][u + 512] = accB;  // lane-contiguous, conflict-free
    __syncthreads();  // A: all partials complete
    if (t < HD) {
      const float zi = (float)(zpart[0][t] + zpart[1][t]) * dq + xg0;
      const float zf =
          (float)(zpart[0][HD + t] + zpart[1][HD + t]) * dq + xg1;
      const float zg =
          (float)(zpart[0][2 * HD + t] + zpart[1][2 * HD + t]) * dq + xg2;
      const float zo =
          (float)(zpart[0][3 * HD + t] + zpart[1][3 * HD + t]) * dq + xg3;
      const float ig = fsigm(zi), fg = fsigm(zf), gg = ftanh(zg),
                  og = fsigm(zo);
      const float cv = fg * cst + ig * gg;
      cst = cv;
      const float hv = og * ftanh(cv);
      hout[(size_t)tt * HD + t] = hv;
      const int hqv = (int)rintf(fminf(fmaxf(hv * 127.f, -127.f), 127.f));
      ((unsigned char*)&hq[par ^ 1][0])[t] = (unsigned char)(hqv & 255);
    }
    __syncthreads();  // B: next-step h ready
  }
}

// ---------------- K3: feats = [hf|hb] @ W_out^T + b_out ----------------
__global__ __launch_bounds__(256) void feats_kernel(
    const float* __restrict__ hf, const float* __restrict__ hb,
    const float* __restrict__ Wout, const float* __restrict__ bout,
    float* __restrict__ feats) {
  __shared__ float Ws[NTAG][520];
  __shared__ float bs[NTAG];
  const int tid = threadIdx.x;
  for (int i = tid; i < NTAG * 512; i += 256) Ws[i / 512][i % 512] = Wout[i];
  if (tid < NTAG) bs[tid] = bout[tid];
  __syncthreads();
  const int t0 = blockIdx.x * 32;
  for (int idx = tid; idx < 32 * NTAG; idx += 256) {
    const int t = t0 + idx / NTAG;
    const int tag = idx % NTAG;
    const float* __restrict__ hfr = &hf[t * HD];
    const float* __restrict__ hbr = &hb[t * HD];
    float s = bs[tag];
#pragma unroll 8
    for (int k = 0; k < HD; ++k) {
      s += hfr[k] * Ws[tag][k];
      s += hbr[k] * Ws[tag][HD + k];
    }
    feats[t * NTAG + tag] = s;
  }
}

// ---------------- K4a: per-chunk max-plus matrix (parallel over 256 chunks) --
__global__ __launch_bounds__(64) void vit_chunkM(
    const float* __restrict__ feats, const float* __restrict__ trans,
    float* __restrict__ M) {
  const int c = blockIdx.x;
  const int lane = threadIdx.x;
  const int p = lane < NTAG ? lane : 0;
  __shared__ float trL[NTAG * NTAG];
  for (int i = lane; i < NTAG * NTAG; i += 64) trL[i] = trans[i];
  const int t0 = c * CH;
  float ft_cur = feats[(size_t)t0 * NTAG + p];
  float ft_next = feats[(size_t)(t0 + 1) * NTAG + p];
  __syncthreads();
  float m[NTAG];
#pragma unroll
  for (int n = 0; n < NTAG; ++n) m[n] = trL[n * NTAG + p] + rlf(ft_cur, n);
  for (int s = 1; s < CH; ++s) {
    ft_cur = ft_next;
    if (s + 1 < CH) ft_next = feats[(size_t)(t0 + s + 1) * NTAG + p];
    float nm[NTAG];
#pragma unroll
    for (int n = 0; n < NTAG; ++n) {
      float b = trL[n * NTAG + 0] + m[0];
#pragma unroll
      for (int qq = 1; qq < NTAG; ++qq)
        b = fmaxf(b, trL[n * NTAG + qq] + m[qq]);
      nm[n] = b + rlf(ft_cur, n);
    }
#pragma unroll
    for (int n = 0; n < NTAG; ++n) m[n] = nm[n];
  }
  if (lane < NTAG) {
#pragma unroll
    for (int qq = 0; qq < NTAG; ++qq)
      M[(size_t)c * (NTAG * NTAG) + qq * NTAG + lane] = m[qq];
  }
}

// ---------------- K4b: serial compose over 256 chunk matrices (1 wave) -------
__global__ __launch_bounds__(64) void vit_compose(
    const float* __restrict__ M, const float* __restrict__ trans,
    float* __restrict__ fvst, float* __restrict__ out, int* __restrict__ blp) {
  const int lane = threadIdx.x;
  const int n = lane < NTAG ? lane : 0;
  float fv = (lane == TAG_START) ? 0.0f : NEGV;
  const float* Mr = M + (size_t)n * NTAG;
  float4 r0 = *(const float4*)(Mr + 0), r1 = *(const float4*)(Mr + 4);
  float4 r2 = *(const float4*)(Mr + 8), r3 = *(const float4*)(Mr + 12);
  float4 r4 = *(const float4*)(Mr + 16);
  for (int c = 0; c < NCH; ++c) {
    if (lane < NTAG) fvst[c * NTAG + lane] = fv;
    const float4 c0 = r0, c1 = r1, c2 = r2, c3 = r3, c4 = r4;
    if (c + 1 < NCH) {
      const float* Mn = M + (size_t)(c + 1) * (NTAG * NTAG) + n * NTAG;
      r0 = *(const float4*)(Mn + 0);
      r1 = *(const float4*)(Mn + 4);
      r2 = *(const float4*)(Mn + 8);
      r3 = *(const float4*)(Mn + 12);
      r4 = *(const float4*)(Mn + 16);
    }
    const float mr[NTAG] = {c0.x, c0.y, c0.z, c0.w, c1.x, c1.y, c1.z,
                            c1.w, c2.x, c2.y, c2.z, c2.w, c3.x, c3.y,
                            c3.z, c3.w, c4.x, c4.y, c4.z, c4.w};
    float b = mr[0] + rlf(fv, 0);
#pragma unroll
    for (int pp = 1; pp < NTAG; ++pp) b = fmaxf(b, mr[pp] + rlf(fv, pp));
    fv = b;
  }
  const float term = fv + trans[TAG_STOP * NTAG + n];
  float bb = rlf(term, 0);
  int bi = 0;
#pragma unroll
  for (int pp = 1; pp < NTAG; ++pp) {
    const float v = rlf(term, pp);
    if (v > bb) {
      bb = v;
      bi = pp;
    }
  }
  if (lane == 0) {
    out[0] = bb;
    *blp = bi;
  }
}

// ---------------- K4c: per-chunk replay (bp + candidate paths + fmap) --------
__global__ __launch_bounds__(64) void vit_replay(
    const float* __restrict__ feats, const float* __restrict__ trans,
    const float* __restrict__ fvst, unsigned char* __restrict__ pcand,
    unsigned char* __restrict__ fmap) {
  const int c = blockIdx.x;
  const int lane = threadIdx.x;
  const int nt = lane < NTAG ? lane : 0;
  __shared__ unsigned char bpL[CH][NTAG];
  float tr[NTAG];
#pragma unroll
  for (int p = 0; p < NTAG; ++p) tr[p] = trans[nt * NTAG + p];
  float fv = (lane < NTAG) ? fvst[c * NTAG + lane] : NEGV;
  const int t0 = c * CH;
  float fc_cur = feats[(size_t)t0 * NTAG + nt];
  float fc_next = feats[(size_t)(t0 + 1) * NTAG + nt];
  for (int s = 0; s < CH; ++s) {
    float b0 = -3.4e38f, b1 = -3.4e38f, b2 = -3.4e38f, b3 = -3.4e38f;
    int i0 = 0, i1 = 0, i2 = 0, i3 = 0;
#define CAND(p, B, I)                 \
  {                                   \
    const float fvp = rlf(fv, (p));   \
    const float v = fvp + tr[p];      \
    if (v > B) {                      \
      B = v;                          \
      I = (p);                        \
    }                                 \
  }
    CAND(0, b0, i0) CAND(1, b0, i0) CAND(2, b0, i0) CAND(3, b0, i0)
    CAND(4, b0, i0)
    CAND(5, b1, i1) CAND(6, b1, i1) CAND(7, b1, i1) CAND(8, b1, i1)
    CAND(9, b1, i1)
    CAND(10, b2, i2) CAND(11, b2, i2) CAND(12, b2, i2) CAND(13, b2, i2)
    CAND(14, b2, i2)
    CAND(15, b3, i3) CAND(16, b3, i3) CAND(17, b3, i3) CAND(18, b3, i3)
    CAND(19, b3, i3)
#undef CAND
    float best = b0;
    int bi = i0;
    if (b1 > best) { best = b1; bi = i1; }
    if (b2 > best) { best = b2; bi = i2; }
    if (b3 > best) { best = b3; bi = i3; }
    fv = best + fc_cur;
    if (lane < NTAG) bpL[s][lane] = (unsigned char)bi;
    fc_cur = fc_next;
    if (s + 2 < CH) fc_next = feats[(size_t)(t0 + s + 2) * NTAG + nt];
  }
  __syncthreads();
  if (lane < NTAG) {
    unsigned char loc[CH];
    int cur = lane;
    loc[CH - 1] = (unsigned char)cur;
#pragma unroll
    for (int s2 = CH - 1; s2 >= 1; --s2) {
      cur = bpL[s2][cur];
      loc[s2 - 1] = (unsigned char)cur;
    }
    fmap[c * NTAG + lane] = bpL[0][cur];
    u32 w0 = (u32)loc[0] | ((u32)loc[1] << 8) | ((u32)loc[2] << 16) |
             ((u32)loc[3] << 24);
    u32 w1 = (u32)loc[4] | ((u32)loc[5] << 8) | ((u32)loc[6] << 16) |
             ((u32)loc[7] << 24);
    u32 w2 = (u32)loc[8] | ((u32)loc[9] << 8) | ((u32)loc[10] << 16) |
             ((u32)loc[11] << 24);
    u32 w3 = (u32)loc[12] | ((u32)loc[13] << 8) | ((u32)loc[14] << 16) |
             ((u32)loc[15] << 24);
    uint4 w;
    w.x = w0;
    w.y = w1;
    w.z = w2;
    w.w = w3;
    *(uint4*)&pcand[((size_t)c * NTAG + lane) * CH] = w;
  }
}

// ---------------- K4d: chain fmaps + emit path ----------------
__global__ __launch_bounds__(64) void vit_final(
    const unsigned char* __restrict__ pcand,
    const unsigned char* __restrict__ fmap, const int* __restrict__ blp,
    float* __restrict__ out) {
  __shared__ unsigned char fm[NCH * NTAG];
  __shared__ short bnd[NCH];
  const int lane = threadIdx.x;
  for (int i = lane; i < NCH * NTAG; i += 64) fm[i] = fmap[i];
  __syncthreads();
  if (lane == 0) {
    int cur = *blp;
    bnd[NCH - 1] = (short)cur;
    for (int c = NCH - 1; c >= 1; --c) {
      cur = fm[c * NTAG + cur];
      bnd[c - 1] = (short)cur;
    }
  }
  __syncthreads();
  for (int cc = lane; cc < NCH; cc += 64) {
    const int e = bnd[cc];
    const uint4 w = *(const uint4*)&pcand[((size_t)cc * NTAG + e) * CH];
    const u32 ws[4] = {w.x, w.y, w.z, w.w};
#pragma unroll
    for (int j = 0; j < 4; ++j) {
#pragma unroll
      for (int b = 0; b < 4; ++b) {
        out[1 + cc * CH + j * 4 + b] = (float)((ws[j] >> (8 * b)) & 255u);
      }
    }
  }
}

extern "C" void kernel_launch(void* const* d_in, const int* in_sizes, int n_in,
                              void* d_out, int out_size, void* d_ws,
                              size_t ws_size, hipStream_t stream) {
  const int* sentence = (const int*)d_in[0];
  const float* etab = (const float*)d_in[1];
  const float* Wihf = (const float*)d_in[2];
  const float* Whhf = (const float*)d_in[3];
  const float* bihf = (const float*)d_in[4];
  const float* bhhf = (const float*)d_in[5];
  const float* Wihb = (const float*)d_in[6];
  const float* Whhb = (const float*)d_in[7];
  const float* bihb = (const float*)d_in[8];
  const float* bhhb = (const float*)d_in[9];
  const float* Wout = (const float*)d_in[10];
  const float* bout = (const float*)d_in[11];
  const float* trans = (const float*)d_in[12];
  const float* h0 = (const float*)d_in[13];
  const float* c0 = (const float*)d_in[14];

  float* ws = (float*)d_ws;
  float* xpf = ws;
  float* xpb = xpf + (size_t)LSEQ * GD;
  float* hfp = xpb + (size_t)LSEQ * GD;
  float* hbp = hfp + (size_t)LSEQ * HD;
  float* feats = hbp + (size_t)LSEQ * HD;
  float* Mv = feats + (size_t)LSEQ * NTAG;          // 256*400 floats
  float* fvst = Mv + (size_t)NCH * NTAG * NTAG;     // 256*20 floats
  int* blp = (int*)(fvst + (size_t)NCH * NTAG);     // 4 ints reserved
  unsigned char* pcand = (unsigned char*)(blp + 4); // 256*20*16 bytes
  unsigned char* fmapb = pcand + (size_t)NCH * NTAG * CH;  // 256*20 bytes
  float* outp = (float*)d_out;

  xp_gemm<<<dim3(GD / 64, LSEQ / 64, 2), 256, 0, stream>>>(
      sentence, etab, Wihf, Wihb, bihf, bhhf, bihb, bhhb, xpf, xpb);
  lstm_scan<<<2, 1024, 0, stream>>>(Whhf, Whhb, xpf, xpb, h0, c0, hfp, hbp);
  feats_kernel<<<LSEQ / 32, 256, 0, stream>>>(hfp, hbp, Wout, bout, feats);
  vit_chunkM<<<NCH, 64, 0, stream>>>(feats, trans, Mv);
  vit_compose<<<1, 64, 0, stream>>>(Mv, trans, fvst, outp, blp);
  vit_replay<<<NCH, 64, 0, stream>>>(feats, trans, fvst, pcand, fmapb);
  vit_final<<<1, 64, 0, stream>>>(pcand, fmapb, blp, outp);
}